// Round 2
// baseline (322.807 us; speedup 1.0000x reference)
//
#include <hip/hip_runtime.h>
#include <hip/hip_cooperative_groups.h>

namespace cg = cooperative_groups;

// Augmenter: B=128, C=3, H=W=256, fp32.
// out_c = c2*s2*(x_c - cm) + c2*(cm - gm) + gm + b1   (color ops fused)
// then translate (zero pad) on source coords, cutout rect (zero) on dest coords.
constexpr int BN  = 128;
constexpr int CN  = 3;
constexpr int HN  = 256;
constexpr int WN  = 256;
constexpr int HW  = HN * WN;       // 65536
constexpr int CHW = CN * HW;       // 196608
constexpr int SHIFT_ = 32;         // int(H*0.125+0.5)
constexpr int CS  = 128;           // int(H*0.5+0.5)
constexpr int NSLICE = 2048;       // 16 slices per batch (16 rows each)

typedef float f32x4 __attribute__((ext_vector_type(4)));

// =====================  Fused cooperative kernel  =========================
// Phase 1: each slice s = (b, j) sums rows [j*16, j*16+16) over all 3
//          channels -> ws[s].   grid.sync().
// Phase 2: same slice mapping applies color/translate/cutout and stores.
// Slice-persistent: correct for any grid size.
__global__ __launch_bounds__(256, 4) void aug_fused(
    const float* __restrict__ x,
    const float* __restrict__ br, const float* __restrict__ sat,
    const float* __restrict__ con,
    const int* __restrict__ tx, const int* __restrict__ ty,
    const int* __restrict__ cx, const int* __restrict__ cy,
    float* __restrict__ ws, float* __restrict__ out)
{
    const int t   = threadIdx.x;
    const int nwg = gridDim.x;

    __shared__ float sm[4];
    __shared__ float s_gm;

    // ---------------- Phase 1: per-slice partial sums ----------------
    for (int s = blockIdx.x; s < NSLICE; s += nwg) {
        const int b = s >> 4;
        const int j = s & 15;
        const float4* base = reinterpret_cast<const float4*>(x + (size_t)b * CHW);
        float a0 = 0.f, a1 = 0.f, a2 = 0.f, a3 = 0.f;
        #pragma unroll
        for (int c = 0; c < CN; ++c) {
            // rows [j*16, j*16+16) of channel c: 1024 float4 starting at
            // c*HW/4 + j*1024
            const float4* p = base + c * (HW / 4) + j * 1024 + t;
            float4 v0 = p[0];
            float4 v1 = p[256];
            float4 v2 = p[512];
            float4 v3 = p[768];
            a0 += (v0.x + v0.y) + (v0.z + v0.w);
            a1 += (v1.x + v1.y) + (v1.z + v1.w);
            a2 += (v2.x + v2.y) + (v2.z + v2.w);
            a3 += (v3.x + v3.y) + (v3.z + v3.w);
        }
        float v = (a0 + a1) + (a2 + a3);
        #pragma unroll
        for (int off = 32; off > 0; off >>= 1) v += __shfl_down(v, off, 64);
        if ((t & 63) == 0) sm[t >> 6] = v;
        __syncthreads();
        if (t == 0) ws[s] = (sm[0] + sm[1]) + (sm[2] + sm[3]);
        __syncthreads();   // protect sm before next slice iteration
    }

    cg::this_grid().sync();

    // ---------------- Phase 2: apply ----------------
    for (int s = blockIdx.x; s < NSLICE; s += nwg) {
        const int b = s >> 4;
        const int j = s & 15;

        if (t == 0) {
            float g = 0.f;
            #pragma unroll
            for (int i = 0; i < 16; ++i) g += ws[b * 16 + i];
            s_gm = g * (1.0f / (float)CHW);
        }
        __syncthreads();
        const float gm = s_gm;

        const float b1 = br[b] - 0.5f;
        const float c2 = con[b] + 0.5f;
        const float k  = c2 * (sat[b] * 2.0f);
        const int txs  = tx[b] - SHIFT_;
        const int tys  = ty[b] - SHIFT_;
        const int cx0  = cx[b] - CS / 2;
        const int cy0  = cy[b] - CS / 2;
        const int h0   = max(cx0, 0), h1 = min(cx0 + CS - 1, HN - 1);
        const int wc0  = max(cy0, 0), wc1 = min(cy0 + CS - 1, WN - 1);

        for (int it = 0; it < 4; ++it) {
            const int lp = ((it << 8) + t) << 2;     // local pixel 0..4095 (x4)
            const int h  = (j << 4) + (lp >> 8);
            const int w0 = lp & (WN - 1);
            const int p0 = (h << 8) + w0;            // pixel index in image

            const int sh  = h  + txs;
            const int sw0 = w0 + tys;

            const bool rowok   = (sh >= 0) & (sh < HN);
            const bool cut_row = (h >= h0) & (h <= h1);
            const bool cut_all = cut_row & (w0 >= wc0) & (w0 + 3 <= wc1);

            float x0[4], x1[4], x2[4];
            bool  valid[4];

            if (rowok & !cut_all) {
                const float* basep = x + (size_t)b * CHW + sh * WN + sw0;
                if (sw0 >= 0 && sw0 + 3 < WN) {
                    float4 a, bb, c;
                    __builtin_memcpy(&a,  basep,          sizeof(float4));
                    __builtin_memcpy(&bb, basep + HW,     sizeof(float4));
                    __builtin_memcpy(&c,  basep + 2 * HW, sizeof(float4));
                    x0[0]=a.x;  x0[1]=a.y;  x0[2]=a.z;  x0[3]=a.w;
                    x1[0]=bb.x; x1[1]=bb.y; x1[2]=bb.z; x1[3]=bb.w;
                    x2[0]=c.x;  x2[1]=c.y;  x2[2]=c.z;  x2[3]=c.w;
                    #pragma unroll
                    for (int i = 0; i < 4; ++i) valid[i] = true;
                } else {
                    #pragma unroll
                    for (int i = 0; i < 4; ++i) {
                        const int sw = sw0 + i;
                        const bool ok = (sw >= 0) & (sw < WN);
                        valid[i] = ok;
                        if (ok) {
                            x0[i] = basep[i];
                            x1[i] = basep[i + HW];
                            x2[i] = basep[i + 2 * HW];
                        } else {
                            x0[i] = x1[i] = x2[i] = 0.f;
                        }
                    }
                }
            } else {
                #pragma unroll
                for (int i = 0; i < 4; ++i) { x0[i]=x1[i]=x2[i]=0.f; valid[i]=false; }
            }

            f32x4 o0, o1, o2;
            #pragma unroll
            for (int i = 0; i < 4; ++i) {
                const int w = w0 + i;
                const bool cut  = cut_row & (w >= wc0) & (w <= wc1);
                const bool live = valid[i] & !cut;
                const float cm  = (x0[i] + x1[i] + x2[i]) * (1.0f / 3.0f);
                const float add = c2 * (cm - gm) + gm + b1;
                o0[i] = live ? (k * (x0[i] - cm) + add) : 0.f;
                o1[i] = live ? (k * (x1[i] - cm) + add) : 0.f;
                o2[i] = live ? (k * (x2[i] - cm) + add) : 0.f;
            }

            f32x4* ob = reinterpret_cast<f32x4*>(out + (size_t)b * CHW + p0);
            __builtin_nontemporal_store(o0, ob);
            __builtin_nontemporal_store(o1, ob + HW / 4);
            __builtin_nontemporal_store(o2, ob + 2 * (HW / 4));
        }
        __syncthreads();   // protect s_gm before next slice iteration
    }
}

// =====================  Fallback: verified two-kernel path  ===============
constexpr int RBLK = 8;

__global__ __launch_bounds__(256) void aug_reduce(const float* __restrict__ x,
                                                  float* __restrict__ partial) {
    const int j = blockIdx.x;
    const int b = blockIdx.y;
    const int t = threadIdx.x;
    constexpr int PER_BLOCK = CHW / 4 / RBLK;
    constexpr int ITER = PER_BLOCK / 256;
    const float4* p = reinterpret_cast<const float4*>(x + (size_t)b * CHW)
                      + (size_t)j * PER_BLOCK + t;
    float s0 = 0.f, s1 = 0.f, s2 = 0.f, s3 = 0.f;
    #pragma unroll
    for (int i = 0; i < ITER; i += 4) {
        float4 v0 = p[(i + 0) * 256];
        float4 v1 = p[(i + 1) * 256];
        float4 v2 = p[(i + 2) * 256];
        float4 v3 = p[(i + 3) * 256];
        s0 += (v0.x + v0.y) + (v0.z + v0.w);
        s1 += (v1.x + v1.y) + (v1.z + v1.w);
        s2 += (v2.x + v2.y) + (v2.z + v2.w);
        s3 += (v3.x + v3.y) + (v3.z + v3.w);
    }
    float s = (s0 + s1) + (s2 + s3);
    #pragma unroll
    for (int off = 32; off > 0; off >>= 1) s += __shfl_down(s, off, 64);
    __shared__ float sm[4];
    if ((t & 63) == 0) sm[t >> 6] = s;
    __syncthreads();
    if (t == 0) partial[b * RBLK + j] = (sm[0] + sm[1]) + (sm[2] + sm[3]);
}

__global__ __launch_bounds__(256) void aug_apply(
    const float* __restrict__ x,
    const float* __restrict__ br, const float* __restrict__ sat,
    const float* __restrict__ con,
    const int* __restrict__ tx, const int* __restrict__ ty,
    const int* __restrict__ cx, const int* __restrict__ cy,
    const float* __restrict__ partial, float* __restrict__ out)
{
    const int b  = blockIdx.y;
    const int g  = blockIdx.x * 256 + threadIdx.x;
    const int p0 = g << 2;
    const int h  = p0 >> 8;
    const int w0 = p0 & (WN - 1);

    __shared__ float s_gm;
    if (threadIdx.x == 0) {
        float s = 0.f;
        #pragma unroll
        for (int i = 0; i < RBLK; ++i) s += partial[b * RBLK + i];
        s_gm = s * (1.0f / (float)CHW);
    }
    __syncthreads();
    const float gm = s_gm;

    const float b1 = br[b] - 0.5f;
    const float k  = (con[b] + 0.5f) * (sat[b] * 2.0f);
    const float c2 = con[b] + 0.5f;

    const int sh  = h  + (tx[b] - SHIFT_);
    const int sw0 = w0 + (ty[b] - SHIFT_);
    const int cx0 = cx[b] - CS / 2;
    const int cy0 = cy[b] - CS / 2;
    const int h0 = max(cx0, 0), h1 = min(cx0 + CS - 1, HN - 1);
    const int wc0 = max(cy0, 0), wc1 = min(cy0 + CS - 1, WN - 1);

    const bool rowok   = (sh >= 0) & (sh < HN);
    const bool cut_row = (h >= h0) & (h <= h1);
    const bool cut_all = cut_row & (w0 >= wc0) & (w0 + 3 <= wc1);

    float x0[4], x1[4], x2[4];
    bool  valid[4];

    if (rowok & !cut_all) {
        const float* base = x + (size_t)b * CHW + sh * WN + sw0;
        if (sw0 >= 0 && sw0 + 3 < WN) {
            float4 a, bb, c;
            __builtin_memcpy(&a,  base,          sizeof(float4));
            __builtin_memcpy(&bb, base + HW,     sizeof(float4));
            __builtin_memcpy(&c,  base + 2 * HW, sizeof(float4));
            x0[0]=a.x;  x0[1]=a.y;  x0[2]=a.z;  x0[3]=a.w;
            x1[0]=bb.x; x1[1]=bb.y; x1[2]=bb.z; x1[3]=bb.w;
            x2[0]=c.x;  x2[1]=c.y;  x2[2]=c.z;  x2[3]=c.w;
            #pragma unroll
            for (int i = 0; i < 4; ++i) valid[i] = true;
        } else {
            #pragma unroll
            for (int i = 0; i < 4; ++i) {
                const int sw = sw0 + i;
                const bool ok = (sw >= 0) & (sw < WN);
                valid[i] = ok;
                if (ok) {
                    x0[i] = base[i];
                    x1[i] = base[i + HW];
                    x2[i] = base[i + 2 * HW];
                } else {
                    x0[i] = x1[i] = x2[i] = 0.f;
                }
            }
        }
    } else {
        #pragma unroll
        for (int i = 0; i < 4; ++i) { x0[i]=x1[i]=x2[i]=0.f; valid[i]=false; }
    }

    f32x4 o0, o1, o2;
    #pragma unroll
    for (int i = 0; i < 4; ++i) {
        const int w = w0 + i;
        const bool cut = cut_row & (w >= wc0) & (w <= wc1);
        const bool live = valid[i] & !cut;
        const float cm  = (x0[i] + x1[i] + x2[i]) * (1.0f / 3.0f);
        const float add = c2 * (cm - gm) + gm + b1;
        o0[i] = live ? (k * (x0[i] - cm) + add) : 0.f;
        o1[i] = live ? (k * (x1[i] - cm) + add) : 0.f;
        o2[i] = live ? (k * (x2[i] - cm) + add) : 0.f;
    }

    f32x4* ob = reinterpret_cast<f32x4*>(out + (size_t)b * CHW + p0);
    __builtin_nontemporal_store(o0, ob);
    __builtin_nontemporal_store(o1, ob + HW / 4);
    __builtin_nontemporal_store(o2, ob + 2 * (HW / 4));
}

// ==========================================================================
extern "C" void kernel_launch(void* const* d_in, const int* in_sizes, int n_in,
                              void* d_out, int out_size, void* d_ws, size_t ws_size,
                              hipStream_t stream) {
    const float* imgs = (const float*)d_in[0];
    const float* br   = (const float*)d_in[1];
    const float* sat  = (const float*)d_in[2];
    const float* con  = (const float*)d_in[3];
    const int*   tx   = (const int*)d_in[4];
    const int*   ty   = (const int*)d_in[5];
    const int*   cx   = (const int*)d_in[6];
    const int*   cy   = (const int*)d_in[7];
    float* out = (float*)d_out;
    float* ws  = (float*)d_ws;   // NSLICE floats = 8 KiB

    // Size grid from the occupancy query (cooperative launch must fit
    // co-resident). Cached: pure host query, graph-capture-safe.
    static int s_grid = 0;
    if (s_grid == 0) {
        int nb = 0;
        hipError_t qe = hipOccupancyMaxActiveBlocksPerMultiprocessor(&nb, aug_fused, 256, 0);
        if (qe != hipSuccess || nb < 1) nb = 1;
        long g = (long)nb * 256;          // 256 CUs on MI355X
        if (g > NSLICE) g = NSLICE;
        s_grid = (int)g;
    }

    void* args[] = {
        (void*)&imgs, (void*)&br, (void*)&sat, (void*)&con,
        (void*)&tx, (void*)&ty, (void*)&cx, (void*)&cy,
        (void*)&ws, (void*)&out
    };
    hipError_t err = hipLaunchCooperativeKernel(
        (const void*)aug_fused, dim3(s_grid), dim3(256), args, 0, stream);

    if (err != hipSuccess) {
        // Fallback: verified two-kernel path.
        aug_reduce<<<dim3(RBLK, BN), 256, 0, stream>>>(imgs, ws);
        aug_apply<<<dim3(HW / 4 / 256, BN), 256, 0, stream>>>(imgs, br, sat, con,
                                                              tx, ty, cx, cy, ws, out);
    }
}

// Round 3
// 239.186 us; speedup vs baseline: 1.3496x; 1.3496x over previous
//
#include <hip/hip_runtime.h>

// Augmenter: B=128, C=3, H=W=256, fp32.
// out_c = c2*s2*(x_c - cm) + c2*(cm - gm) + gm + b1   (color ops fused)
// then translate (zero pad) on source coords, cutout rect (zero) on dest coords.
//
// R3: MEASUREMENT ROUND. Kernels byte-identical to the verified R1 pair;
// kernel_launch enqueues the (idempotent) pair TWICE. dur_us - 198.5 gives
// the L3-warm pair time directly, resolving whether the pair is ~40 us
// (near roofline) or ~120 us (3x headroom).
constexpr int BN  = 128;
constexpr int CN  = 3;
constexpr int HN  = 256;
constexpr int WN  = 256;
constexpr int HW  = HN * WN;       // 65536
constexpr int CHW = CN * HW;       // 196608
constexpr int SHIFT_ = 32;         // int(H*0.125+0.5)
constexpr int CS  = 128;           // int(H*0.5+0.5)
constexpr int RBLK = 8;            // reduce blocks per batch

typedef float f32x4 __attribute__((ext_vector_type(4)));

// --- Kernel 1: per-batch partial sums (for global mean) -------------------
__global__ __launch_bounds__(256) void aug_reduce(const float* __restrict__ x,
                                                  float* __restrict__ partial) {
    const int j = blockIdx.x;          // chunk within batch, 0..RBLK-1
    const int b = blockIdx.y;          // batch
    const int t = threadIdx.x;
    constexpr int PER_BLOCK = CHW / 4 / RBLK;   // 6144 float4 per block
    constexpr int ITER = PER_BLOCK / 256;       // 24
    const float4* p = reinterpret_cast<const float4*>(x + (size_t)b * CHW)
                      + (size_t)j * PER_BLOCK + t;
    float s0 = 0.f, s1 = 0.f, s2 = 0.f, s3 = 0.f;
    #pragma unroll
    for (int i = 0; i < ITER; i += 4) {
        float4 v0 = p[(i + 0) * 256];
        float4 v1 = p[(i + 1) * 256];
        float4 v2 = p[(i + 2) * 256];
        float4 v3 = p[(i + 3) * 256];
        s0 += (v0.x + v0.y) + (v0.z + v0.w);
        s1 += (v1.x + v1.y) + (v1.z + v1.w);
        s2 += (v2.x + v2.y) + (v2.z + v2.w);
        s3 += (v3.x + v3.y) + (v3.z + v3.w);
    }
    float s = (s0 + s1) + (s2 + s3);
    #pragma unroll
    for (int off = 32; off > 0; off >>= 1) s += __shfl_down(s, off, 64);
    __shared__ float sm[4];
    if ((t & 63) == 0) sm[t >> 6] = s;
    __syncthreads();
    if (t == 0) partial[b * RBLK + j] = (sm[0] + sm[1]) + (sm[2] + sm[3]);
}

// --- Kernel 2: fused color transform + translate + cutout, 4 px/thread ----
__global__ __launch_bounds__(256) void aug_apply(
    const float* __restrict__ x,
    const float* __restrict__ br, const float* __restrict__ sat,
    const float* __restrict__ con,
    const int* __restrict__ tx, const int* __restrict__ ty,
    const int* __restrict__ cx, const int* __restrict__ cy,
    const float* __restrict__ partial, float* __restrict__ out)
{
    const int b  = blockIdx.y;
    const int g  = blockIdx.x * 256 + threadIdx.x;
    const int p0 = g << 2;
    const int h  = p0 >> 8;
    const int w0 = p0 & (WN - 1);

    __shared__ float s_gm;
    if (threadIdx.x == 0) {
        float s = 0.f;
        #pragma unroll
        for (int i = 0; i < RBLK; ++i) s += partial[b * RBLK + i];
        s_gm = s * (1.0f / (float)CHW);
    }
    __syncthreads();
    const float gm = s_gm;

    const float b1 = br[b] - 0.5f;
    const float k  = (con[b] + 0.5f) * (sat[b] * 2.0f);
    const float c2 = con[b] + 0.5f;

    const int sh  = h  + (tx[b] - SHIFT_);
    const int sw0 = w0 + (ty[b] - SHIFT_);
    const int cx0 = cx[b] - CS / 2;
    const int cy0 = cy[b] - CS / 2;
    const int h0 = max(cx0, 0), h1 = min(cx0 + CS - 1, HN - 1);
    const int wc0 = max(cy0, 0), wc1 = min(cy0 + CS - 1, WN - 1);

    const bool rowok   = (sh >= 0) & (sh < HN);
    const bool cut_row = (h >= h0) & (h <= h1);
    const bool cut_all = cut_row & (w0 >= wc0) & (w0 + 3 <= wc1);

    float x0[4], x1[4], x2[4];
    bool  valid[4];

    if (rowok & !cut_all) {
        const float* base = x + (size_t)b * CHW + sh * WN + sw0;
        if (sw0 >= 0 && sw0 + 3 < WN) {
            float4 a, bb, c;
            __builtin_memcpy(&a,  base,          sizeof(float4));
            __builtin_memcpy(&bb, base + HW,     sizeof(float4));
            __builtin_memcpy(&c,  base + 2 * HW, sizeof(float4));
            x0[0]=a.x;  x0[1]=a.y;  x0[2]=a.z;  x0[3]=a.w;
            x1[0]=bb.x; x1[1]=bb.y; x1[2]=bb.z; x1[3]=bb.w;
            x2[0]=c.x;  x2[1]=c.y;  x2[2]=c.z;  x2[3]=c.w;
            #pragma unroll
            for (int i = 0; i < 4; ++i) valid[i] = true;
        } else {
            #pragma unroll
            for (int i = 0; i < 4; ++i) {
                const int sw = sw0 + i;
                const bool ok = (sw >= 0) & (sw < WN);
                valid[i] = ok;
                if (ok) {
                    x0[i] = base[i];
                    x1[i] = base[i + HW];
                    x2[i] = base[i + 2 * HW];
                } else {
                    x0[i] = x1[i] = x2[i] = 0.f;
                }
            }
        }
    } else {
        #pragma unroll
        for (int i = 0; i < 4; ++i) { x0[i]=x1[i]=x2[i]=0.f; valid[i]=false; }
    }

    f32x4 o0, o1, o2;
    #pragma unroll
    for (int i = 0; i < 4; ++i) {
        const int w = w0 + i;
        const bool cut = cut_row & (w >= wc0) & (w <= wc1);
        const bool live = valid[i] & !cut;
        const float cm  = (x0[i] + x1[i] + x2[i]) * (1.0f / 3.0f);
        const float add = c2 * (cm - gm) + gm + b1;
        o0[i] = live ? (k * (x0[i] - cm) + add) : 0.f;
        o1[i] = live ? (k * (x1[i] - cm) + add) : 0.f;
        o2[i] = live ? (k * (x2[i] - cm) + add) : 0.f;
    }

    f32x4* ob = reinterpret_cast<f32x4*>(out + (size_t)b * CHW + p0);
    __builtin_nontemporal_store(o0, ob);
    __builtin_nontemporal_store(o1, ob + HW / 4);
    __builtin_nontemporal_store(o2, ob + 2 * (HW / 4));
}

extern "C" void kernel_launch(void* const* d_in, const int* in_sizes, int n_in,
                              void* d_out, int out_size, void* d_ws, size_t ws_size,
                              hipStream_t stream) {
    const float* imgs = (const float*)d_in[0];
    const float* br   = (const float*)d_in[1];
    const float* sat  = (const float*)d_in[2];
    const float* con  = (const float*)d_in[3];
    const int*   tx   = (const int*)d_in[4];
    const int*   ty   = (const int*)d_in[5];
    const int*   cx   = (const int*)d_in[6];
    const int*   cy   = (const int*)d_in[7];
    float* out = (float*)d_out;
    float* partial = (float*)d_ws;   // BN*RBLK floats = 4 KiB

    // Pass 1 (cold): identical to the verified R1 submission.
    aug_reduce<<<dim3(RBLK, BN), 256, 0, stream>>>(imgs, partial);
    aug_apply<<<dim3(HW / 4 / 256, BN), 256, 0, stream>>>(imgs, br, sat, con,
                                                          tx, ty, cx, cy, partial, out);
    // Pass 2 (warm, idempotent): recomputes identical partials and rewrites
    // identical output. dur_us - 198.5 = warm pair time. Measurement only.
    aug_reduce<<<dim3(RBLK, BN), 256, 0, stream>>>(imgs, partial);
    aug_apply<<<dim3(HW / 4 / 256, BN), 256, 0, stream>>>(imgs, br, sat, con,
                                                          tx, ty, cx, cy, partial, out);
}

// Round 4
// 197.031 us; speedup vs baseline: 1.6384x; 1.2139x over previous
//
#include <hip/hip_runtime.h>

// Augmenter: B=128, C=3, H=W=256, fp32.
// out_c = c2*s2*(x_c - cm) + c2*(cm - gm) + gm + b1   (color ops fused)
// then translate (zero pad) on source coords, cutout rect (zero) on dest coords.
//
// FINAL: best-verified two-kernel pair (197.3-198.5 us harness-measured).
// R3 differential measurement: warm pair = 40.7 us vs ~29 us compulsory-
// traffic floor (96 MiB HBM read + 96 MiB NT write @ 6.6 TB/s); the other
// ~145 us of dur_us is harness poison-fill/restore residue (59 us fills at
// 84% HBM peak dominate every top-5). Cooperative fusion measured +130 us
// (grid.sync ~200 us on 2048 blocks, R2); atomic-spin fusion rejected per
// Guideline 16 (dispatch-order-dependent deadlock risk) for <=10 us upside.
constexpr int BN  = 128;
constexpr int CN  = 3;
constexpr int HN  = 256;
constexpr int WN  = 256;
constexpr int HW  = HN * WN;       // 65536
constexpr int CHW = CN * HW;       // 196608
constexpr int SHIFT_ = 32;         // int(H*0.125+0.5)
constexpr int CS  = 128;           // int(H*0.5+0.5)
constexpr int RBLK = 8;            // reduce blocks per batch

typedef float f32x4 __attribute__((ext_vector_type(4)));

// --- Kernel 1: per-batch partial sums (for global mean) -------------------
// ILP: 4 independent accumulators, fully unrolled (24 iters), wave-shuffle
// reduction (1 barrier instead of 8).
__global__ __launch_bounds__(256) void aug_reduce(const float* __restrict__ x,
                                                  float* __restrict__ partial) {
    const int j = blockIdx.x;          // chunk within batch, 0..RBLK-1
    const int b = blockIdx.y;          // batch
    const int t = threadIdx.x;
    constexpr int PER_BLOCK = CHW / 4 / RBLK;   // 6144 float4 per block
    constexpr int ITER = PER_BLOCK / 256;       // 24
    const float4* p = reinterpret_cast<const float4*>(x + (size_t)b * CHW)
                      + (size_t)j * PER_BLOCK + t;
    float s0 = 0.f, s1 = 0.f, s2 = 0.f, s3 = 0.f;
    #pragma unroll
    for (int i = 0; i < ITER; i += 4) {
        float4 v0 = p[(i + 0) * 256];
        float4 v1 = p[(i + 1) * 256];
        float4 v2 = p[(i + 2) * 256];
        float4 v3 = p[(i + 3) * 256];
        s0 += (v0.x + v0.y) + (v0.z + v0.w);
        s1 += (v1.x + v1.y) + (v1.z + v1.w);
        s2 += (v2.x + v2.y) + (v2.z + v2.w);
        s3 += (v3.x + v3.y) + (v3.z + v3.w);
    }
    float s = (s0 + s1) + (s2 + s3);
    #pragma unroll
    for (int off = 32; off > 0; off >>= 1) s += __shfl_down(s, off, 64);
    __shared__ float sm[4];
    if ((t & 63) == 0) sm[t >> 6] = s;
    __syncthreads();
    if (t == 0) partial[b * RBLK + j] = (sm[0] + sm[1]) + (sm[2] + sm[3]);
}

// --- Kernel 2: fused color transform + translate + cutout, 4 px/thread ----
// NT stores: out is never re-read; skipping LLC allocation keeps imgs
// resident in the 256 MiB Infinity Cache for this kernel's own reads.
__global__ __launch_bounds__(256) void aug_apply(
    const float* __restrict__ x,
    const float* __restrict__ br, const float* __restrict__ sat,
    const float* __restrict__ con,
    const int* __restrict__ tx, const int* __restrict__ ty,
    const int* __restrict__ cx, const int* __restrict__ cy,
    const float* __restrict__ partial, float* __restrict__ out)
{
    const int b  = blockIdx.y;
    const int g  = blockIdx.x * 256 + threadIdx.x;   // float4-group index
    const int p0 = g << 2;                           // first pixel of group
    const int h  = p0 >> 8;                          // row (same for all 4)
    const int w0 = p0 & (WN - 1);                    // first col

    // global mean for this batch (sum of RBLK partials), broadcast via LDS
    __shared__ float s_gm;
    if (threadIdx.x == 0) {
        float s = 0.f;
        #pragma unroll
        for (int i = 0; i < RBLK; ++i) s += partial[b * RBLK + i];
        s_gm = s * (1.0f / (float)CHW);
    }
    __syncthreads();
    const float gm = s_gm;

    const float b1 = br[b] - 0.5f;
    const float k  = (con[b] + 0.5f) * (sat[b] * 2.0f);   // c2*s2
    const float c2 = con[b] + 0.5f;

    // translation source coords (zero outside [0,H)x[0,W))
    const int sh  = h  + (tx[b] - SHIFT_);
    const int sw0 = w0 + (ty[b] - SHIFT_);
    // cutout rect on destination coords
    const int cx0 = cx[b] - CS / 2;
    const int cy0 = cy[b] - CS / 2;
    const int h0 = max(cx0, 0), h1 = min(cx0 + CS - 1, HN - 1);
    const int wc0 = max(cy0, 0), wc1 = min(cy0 + CS - 1, WN - 1);

    const bool rowok   = (sh >= 0) & (sh < HN);
    const bool cut_row = (h >= h0) & (h <= h1);
    const bool cut_all = cut_row & (w0 >= wc0) & (w0 + 3 <= wc1);

    float x0[4], x1[4], x2[4];
    bool  valid[4];

    if (rowok & !cut_all) {
        const float* base = x + (size_t)b * CHW + sh * WN + sw0;
        if (sw0 >= 0 && sw0 + 3 < WN) {
            // fast path: 16-B (dword-aligned) vector loads per channel
            float4 a, bb, c;
            __builtin_memcpy(&a,  base,          sizeof(float4));
            __builtin_memcpy(&bb, base + HW,     sizeof(float4));
            __builtin_memcpy(&c,  base + 2 * HW, sizeof(float4));
            x0[0]=a.x;  x0[1]=a.y;  x0[2]=a.z;  x0[3]=a.w;
            x1[0]=bb.x; x1[1]=bb.y; x1[2]=bb.z; x1[3]=bb.w;
            x2[0]=c.x;  x2[1]=c.y;  x2[2]=c.z;  x2[3]=c.w;
            #pragma unroll
            for (int i = 0; i < 4; ++i) valid[i] = true;
        } else {
            // row-edge fallback: masked scalar loads
            #pragma unroll
            for (int i = 0; i < 4; ++i) {
                const int sw = sw0 + i;
                const bool ok = (sw >= 0) & (sw < WN);
                valid[i] = ok;
                if (ok) {
                    x0[i] = base[i];
                    x1[i] = base[i + HW];
                    x2[i] = base[i + 2 * HW];
                } else {
                    x0[i] = x1[i] = x2[i] = 0.f;
                }
            }
        }
    } else {
        #pragma unroll
        for (int i = 0; i < 4; ++i) { x0[i]=x1[i]=x2[i]=0.f; valid[i]=false; }
    }

    f32x4 o0, o1, o2;
    #pragma unroll
    for (int i = 0; i < 4; ++i) {
        const int w = w0 + i;
        const bool cut = cut_row & (w >= wc0) & (w <= wc1);
        const bool live = valid[i] & !cut;
        const float cm  = (x0[i] + x1[i] + x2[i]) * (1.0f / 3.0f);
        const float add = c2 * (cm - gm) + gm + b1;
        o0[i] = live ? (k * (x0[i] - cm) + add) : 0.f;
        o1[i] = live ? (k * (x1[i] - cm) + add) : 0.f;
        o2[i] = live ? (k * (x2[i] - cm) + add) : 0.f;
    }

    f32x4* ob = reinterpret_cast<f32x4*>(out + (size_t)b * CHW + p0);
    __builtin_nontemporal_store(o0, ob);
    __builtin_nontemporal_store(o1, ob + HW / 4);
    __builtin_nontemporal_store(o2, ob + 2 * (HW / 4));
}

extern "C" void kernel_launch(void* const* d_in, const int* in_sizes, int n_in,
                              void* d_out, int out_size, void* d_ws, size_t ws_size,
                              hipStream_t stream) {
    const float* imgs = (const float*)d_in[0];
    const float* br   = (const float*)d_in[1];
    const float* sat  = (const float*)d_in[2];
    const float* con  = (const float*)d_in[3];
    const int*   tx   = (const int*)d_in[4];
    const int*   ty   = (const int*)d_in[5];
    const int*   cx   = (const int*)d_in[6];
    const int*   cy   = (const int*)d_in[7];
    float* out = (float*)d_out;
    float* partial = (float*)d_ws;   // BN*RBLK floats = 4 KiB

    aug_reduce<<<dim3(RBLK, BN), 256, 0, stream>>>(imgs, partial);
    aug_apply<<<dim3(HW / 4 / 256, BN), 256, 0, stream>>>(imgs, br, sat, con,
                                                          tx, ty, cx, cy, partial, out);
}